// Round 1
// 623.995 us; speedup vs baseline: 1.2177x; 1.2177x over previous
//
#include <hip/hip_runtime.h>

// ---- problem constants ----
#define Bn 4
#define Nn 1024
#define Tn 12
#define Cn 256
#define Hn 8
#define DKn 32
#define Mrows 49152            // B*N*T
#define NEl 12582912LL         // B*N*T*C
#define SCALE_ 0.17677669529663687f  // 1/sqrt(32)

typedef __attribute__((ext_vector_type(4))) float f32x4;
typedef __attribute__((ext_vector_type(8))) short s16x8;
typedef __attribute__((ext_vector_type(4))) short s16x4;

__device__ __forceinline__ ushort f2bfu(float x) {       // fp32 -> bf16 (RNE)
    unsigned u = __builtin_bit_cast(unsigned, x);
    u += 0x7fffu + ((u >> 16) & 1u);
    return (ushort)(u >> 16);
}
__device__ __forceinline__ float bfu2f(ushort h) {
    return __builtin_bit_cast(float, ((unsigned)h) << 16);
}

// ---------------- weight pre-conversion: fp32 -> bf16 hi + lo residual ----------------
struct WPtrs { const float* src[7]; };

__global__ __launch_bounds__(256)
void wconv_k(WPtrs w, ushort* __restrict__ Wh, ushort* __restrict__ Wl) {
    int idx = blockIdx.x * 256 + threadIdx.x;   // 7*65536 total, exact grid
    int which = idx >> 16, pos = idx & 65535;
    float x = w.src[which][pos];
    ushort h = f2bfu(x);
    Wh[idx] = h;
    Wl[idx] = f2bfu(x - bfu2f(h));
}

// ---------------- batched GEMM: Y[m,o] = sum_c A[m,c] * W[o,c] (+bias) ----------------
// BM=64, BN=256(full), BK=32; 256 threads = 4 waves; wave w owns cols [64w,64w+64).
// SPLIT: 3-pass bf16x3 (~fp32 accuracy) for the numerically sensitive projections.
struct GPtrs {
    const void*   A[4];
    const ushort* Wh[4];
    const ushort* Wl[4];
    void*         Y[4];
};

template<bool SPLIT, bool IN_BF16, bool OUT_BF16, bool BIAS>
__global__ __launch_bounds__(256)
void gemm_k(GPtrs p, const float* __restrict__ bias) {
    const int bt   = blockIdx.y;
    const int bm   = blockIdx.x * 64;
    const int tid  = threadIdx.x;
    const int lane = tid & 63;
    const int wave = tid >> 6;

    // stride 40 shorts (=80B) to spread LDS banks; keeps 16B alignment
    __shared__ short As[64 * 40];
    __shared__ short Bs[256 * 40];
    __shared__ short Al[SPLIT ? 64 * 40 : 8];
    __shared__ short Bl[SPLIT ? 256 * 40 : 8];

    f32x4 acc[4][4];
#pragma unroll
    for (int i = 0; i < 4; i++)
#pragma unroll
        for (int j = 0; j < 4; j++)
            acc[i][j] = (f32x4){0.f, 0.f, 0.f, 0.f};

    const int r  = tid >> 2;        // 0..63
    const int cq = (tid & 3) * 8;   // 0,8,16,24

    for (int k0 = 0; k0 < 256; k0 += 32) {
        // ---- stage A tile (64 x 32) ----
        if constexpr (IN_BF16) {
            const ushort* A = (const ushort*)p.A[bt];
            s16x8 v = *(const s16x8*)(A + (size_t)(bm + r) * 256 + k0 + cq);
            *(s16x8*)&As[r * 40 + cq] = v;
        } else {
            const float* A = (const float*)p.A[bt];
            const float* g = A + (size_t)(bm + r) * 256 + k0 + cq;
            f32x4 v0 = *(const f32x4*)g;
            f32x4 v1 = *(const f32x4*)(g + 4);
            s16x8 hi, lo;
#pragma unroll
            for (int j = 0; j < 8; j++) {
                float x = (j < 4) ? v0[j] : v1[j - 4];
                ushort hb = f2bfu(x);
                hi[j] = (short)hb;
                if constexpr (SPLIT) lo[j] = (short)f2bfu(x - bfu2f(hb));
            }
            *(s16x8*)&As[r * 40 + cq] = hi;
            if constexpr (SPLIT) *(s16x8*)&Al[r * 40 + cq] = lo;
        }
        // ---- stage W tile (256 x 32), already bf16 ----
#pragma unroll
        for (int pw = 0; pw < 4; pw++) {
            int orow = pw * 64 + r;
            *(s16x8*)&Bs[orow * 40 + cq] =
                *(const s16x8*)(p.Wh[bt] + (size_t)orow * 256 + k0 + cq);
            if constexpr (SPLIT)
                *(s16x8*)&Bl[orow * 40 + cq] =
                    *(const s16x8*)(p.Wl[bt] + (size_t)orow * 256 + k0 + cq);
        }
        __syncthreads();
        // ---- fragments + MFMA ----
        s16x8 a[4], al[4];
#pragma unroll
        for (int mi = 0; mi < 4; mi++) {
            int off = (mi * 16 + (lane & 15)) * 40 + (lane >> 4) * 8;
            a[mi] = *(const s16x8*)&As[off];
            if constexpr (SPLIT) al[mi] = *(const s16x8*)&Al[off];
        }
#pragma unroll
        for (int ni = 0; ni < 4; ni++) {
            int off = (wave * 64 + ni * 16 + (lane & 15)) * 40 + (lane >> 4) * 8;
            s16x8 b = *(const s16x8*)&Bs[off];
            s16x8 bl;
            if constexpr (SPLIT) bl = *(const s16x8*)&Bl[off];
#pragma unroll
            for (int mi = 0; mi < 4; mi++) {
                acc[mi][ni] = __builtin_amdgcn_mfma_f32_16x16x32_bf16(a[mi], b, acc[mi][ni], 0, 0, 0);
                if constexpr (SPLIT) {
                    acc[mi][ni] = __builtin_amdgcn_mfma_f32_16x16x32_bf16(al[mi], b,  acc[mi][ni], 0, 0, 0);
                    acc[mi][ni] = __builtin_amdgcn_mfma_f32_16x16x32_bf16(a[mi],  bl, acc[mi][ni], 0, 0, 0);
                }
            }
        }
        __syncthreads();
    }
    // ---- epilogue: C/D layout col=lane&15, row=(lane>>4)*4+reg ----
#pragma unroll
    for (int mi = 0; mi < 4; mi++) {
#pragma unroll
        for (int ni = 0; ni < 4; ni++) {
            int col  = wave * 64 + ni * 16 + (lane & 15);
            int row0 = bm + mi * 16 + (lane >> 4) * 4;
            float bv = BIAS ? bias[col] : 0.f;
#pragma unroll
            for (int rg = 0; rg < 4; rg++) {
                float v = acc[mi][ni][rg] + bv;
                size_t idx = (size_t)(row0 + rg) * 256 + col;
                if constexpr (OUT_BF16) ((ushort*)p.Y[bt])[idx] = f2bfu(v);
                else                    ((float*)p.Y[bt])[idx]  = v;
            }
        }
    }
}

// ---------------- MFMA attention ----------------
// One wave per (b,n,h). Block = 512 threads = 8 waves = all 8 heads of one (b,n).
// All operands live in registers as 16x16x32 MFMA fragments (rows 12..15 zero).
// Scores computed SWAPPED: D[s][t] = sum_d Y[s][d] X[t][d] with A = s-side matrix,
// so softmax over s = 4 in-lane values + shfl_xor(16) + shfl_xor(32).
// fp32 tensors (Kf, Qs, qf) are hi/lo bf16-split so score math matches fp32.
// P is hi/lo split so P*V keeps fp32-P accuracy against bf16 V.
// Only V needs the transposed B-fragment -> staged once per block in LDS.

#define VSTR 268   // shorts; row stride: 8-byte aligned rows, 8-row offset = +16 banks

__device__ __forceinline__ s16x8 zero8() { s16x8 z = {0,0,0,0,0,0,0,0}; return z; }

__device__ __forceinline__ void split8(f32x4 a, f32x4 b, s16x8& hi, s16x8& lo) {
#pragma unroll
    for (int j = 0; j < 8; j++) {
        float x = (j < 4) ? a[j] : b[j - 4];
        ushort h = f2bfu(x);
        hi[j] = (short)h;
        lo[j] = (short)f2bfu(x - bfu2f(h));
    }
}

// swapped-layout softmax: acc holds S[s=4g+r][t=lane&15] (pre-scale).
// outputs P as a hi/lo-split A-fragment: lane&15 = t (row), k-range = s.
__device__ __forceinline__ void softmax_swapped(f32x4 acc, int g, s16x8& ph, s16x8& pl) {
    float x0 = acc[0] * SCALE_, x1 = acc[1] * SCALE_;
    float x2 = acc[2] * SCALE_, x3 = acc[3] * SCALE_;
    float m = fmaxf(fmaxf(x0, x1), fmaxf(x2, x3));
    m = fmaxf(m, __shfl_xor(m, 16));
    m = fmaxf(m, __shfl_xor(m, 32));        // m >= true max (>=0 from zero pad; safe)
    float e0 = expf(x0 - m), e1 = expf(x1 - m), e2 = expf(x2 - m), e3 = expf(x3 - m);
    if (g == 3) { e0 = 0.f; e1 = 0.f; e2 = 0.f; e3 = 0.f; }   // s=12..15 masked
    float s = e0 + e1 + e2 + e3;
    s += __shfl_xor(s, 16);
    s += __shfl_xor(s, 32);
    float inv = 1.f / s;
    float p0 = e0 * inv, p1 = e1 * inv, p2 = e2 * inv, p3 = e3 * inv;
    // redistribute: group g holds s=4g..4g+3; A-frag group g needs s=8g..8g+7
    float q0 = __shfl_down(p0, 16), q1 = __shfl_down(p1, 16);
    float q2 = __shfl_down(p2, 16), q3 = __shfl_down(p3, 16);
    float w[8];
    if (g == 0) { w[0]=p0; w[1]=p1; w[2]=p2; w[3]=p3; w[4]=q0; w[5]=q1; w[6]=q2; w[7]=q3; }
    else if (g == 1) { w[0]=q0; w[1]=q1; w[2]=q2; w[3]=q3; w[4]=0.f; w[5]=0.f; w[6]=0.f; w[7]=0.f; }
    else { w[0]=0.f; w[1]=0.f; w[2]=0.f; w[3]=0.f; w[4]=0.f; w[5]=0.f; w[6]=0.f; w[7]=0.f; }
#pragma unroll
    for (int j = 0; j < 8; j++) {
        ushort h = f2bfu(w[j]);
        ph[j] = (short)h;
        pl[j] = (short)f2bfu(w[j] - bfu2f(h));
    }
}

// B-fragment of V (col = lane&15 within 16-col half, k = s): gather from LDS columns
__device__ __forceinline__ s16x8 load_vfrag(const ushort* sV, int col, int g) {
    s16x8 v = zero8();
    if (g < 2) {
#pragma unroll
        for (int j = 0; j < 8; j++) {
            int s = 8 * g + j;
            if (s < 12) v[j] = (short)sV[s * VSTR + col];
        }
    }
    return v;
}

__device__ __forceinline__ void ctx_store(s16x8 ph, s16x8 pl, s16x8 vb0, s16x8 vb1,
                                          ushort* __restrict__ dst, size_t abase,
                                          int g, int r16) {
    f32x4 zf = {0.f, 0.f, 0.f, 0.f};
    f32x4 o0 = __builtin_amdgcn_mfma_f32_16x16x32_bf16(ph, vb0, zf, 0, 0, 0);
    o0 = __builtin_amdgcn_mfma_f32_16x16x32_bf16(pl, vb0, o0, 0, 0, 0);
    f32x4 o1 = __builtin_amdgcn_mfma_f32_16x16x32_bf16(ph, vb1, zf, 0, 0, 0);
    o1 = __builtin_amdgcn_mfma_f32_16x16x32_bf16(pl, vb1, o1, 0, 0, 0);
    // D layout: row t = 4g+reg, col d = half*16 + r16; store only t<12 (g<3)
    if (g < 3) {
#pragma unroll
        for (int rg = 0; rg < 4; rg++) {
            size_t row = (size_t)(4 * g + rg) * Cn;
            dst[abase + row + r16]      = f2bfu(o0[rg]);
            dst[abase + row + 16 + r16] = f2bfu(o1[rg]);
        }
    }
}

__global__ __launch_bounds__(512)
void attn_k(const ushort* __restrict__ Qf, const float* __restrict__ Kf,
            const ushort* __restrict__ Vf, const float* __restrict__ Qs,
            const ushort* __restrict__ Ks, const ushort* __restrict__ Vs,
            const float* __restrict__ kj, const float* __restrict__ vf_fs,
            ushort* __restrict__ c0, ushort* __restrict__ c1,
            ushort* __restrict__ c2, ushort* __restrict__ c3)
{
    const int bn   = blockIdx.x;          // b*N + n
    const int tid  = threadIdx.x;
    const int wave = tid >> 6;            // head h = wave
    const int lane = tid & 63;
    const int g    = lane >> 4;           // k-group 0..3
    const int r16  = lane & 15;

    __shared__ ushort sVf[12 * VSTR];
    __shared__ ushort sVs[12 * VSTR];

    // ---- stage Vf, Vs rows (all heads) into LDS, coalesced ----
    if (tid < 384) {
        int t = tid >> 5;                 // 0..11
        int c = (tid & 31) * 8;           // 0..248
        size_t gb = (size_t)bn * (Tn * Cn) + (size_t)t * Cn + c;
        s16x8 vf8 = *(const s16x8*)(Vf + gb);
        s16x8 vs8 = *(const s16x8*)(Vs + gb);
        s16x4 a0 = {vf8[0], vf8[1], vf8[2], vf8[3]};
        s16x4 a1 = {vf8[4], vf8[5], vf8[6], vf8[7]};
        s16x4 b0 = {vs8[0], vs8[1], vs8[2], vs8[3]};
        s16x4 b1 = {vs8[4], vs8[5], vs8[6], vs8[7]};
        *(s16x4*)&sVf[t * VSTR + c]     = a0;
        *(s16x4*)&sVf[t * VSTR + c + 4] = a1;
        *(s16x4*)&sVs[t * VSTR + c]     = b0;
        *(s16x4*)&sVs[t * VSTR + c + 4] = b1;
    }

    // ---- load A/B-style fragments straight from global (row = r16, k = g*8..) ----
    const int  t    = r16;
    const bool tv   = t < 12;
    const int  d0   = g * 8;
    const size_t abase = (size_t)bn * (Tn * Cn) + (size_t)wave * DKn;
    const size_t rb    = abase + (size_t)t * Cn + d0;

    f32x4 z4 = {0.f, 0.f, 0.f, 0.f};
    s16x8 fQf = tv ? *(const s16x8*)(Qf + rb) : zero8();
    s16x8 fKs = tv ? *(const s16x8*)(Ks + rb) : zero8();

    f32x4 kfa = tv ? *(const f32x4*)(Kf + rb)     : z4;
    f32x4 kfb = tv ? *(const f32x4*)(Kf + rb + 4) : z4;
    f32x4 qsa = tv ? *(const f32x4*)(Qs + rb)     : z4;
    f32x4 qsb = tv ? *(const f32x4*)(Qs + rb + 4) : z4;

    s16x8 fKfh, fKfl, fQsh, fQsl;
    split8(kfa, kfb, fKfh, fKfl);
    split8(qsa, qsb, fQsh, fQsl);

    // FlowSpeed physics transform (fp32): qf = kj*(q - q^2/(vf+1e-5))
    float kjt  = tv ? kj[t]    : 0.f;
    float vft  = tv ? vf_fs[t] : 0.f;
    float invv = 1.f / (vft + 1e-5f);
    f32x4 qfa, qfb;
#pragma unroll
    for (int j = 0; j < 4; j++) {
        float qa = qsa[j], qb = qsb[j];
        qfa[j] = kjt * (qa - qa * qa * invv);
        qfb[j] = kjt * (qb - qb * qb * invv);
    }
    s16x8 fqfh, fqfl;
    split8(qfa, qfb, fqfh, fqfl);

    // ---- scores (swapped: D[s][t], A = s-side) ----
    f32x4 zf = {0.f, 0.f, 0.f, 0.f};
    // z_ff: S[t][s] = Qf[t].Kf[s]  -> A=Kf(hi,lo), B=Qf
    f32x4 aff = __builtin_amdgcn_mfma_f32_16x16x32_bf16(fKfh, fQf, zf, 0, 0, 0);
    aff = __builtin_amdgcn_mfma_f32_16x16x32_bf16(fKfl, fQf, aff, 0, 0, 0);
    // z_fs: S[t][s] = Kf[t].qf[s]  -> A=qf(hi,lo), B=Kf(hi,lo): 4-term split
    f32x4 afs = __builtin_amdgcn_mfma_f32_16x16x32_bf16(fqfh, fKfh, zf, 0, 0, 0);
    afs = __builtin_amdgcn_mfma_f32_16x16x32_bf16(fqfl, fKfh, afs, 0, 0, 0);
    afs = __builtin_amdgcn_mfma_f32_16x16x32_bf16(fqfh, fKfl, afs, 0, 0, 0);
    afs = __builtin_amdgcn_mfma_f32_16x16x32_bf16(fqfl, fKfl, afs, 0, 0, 0);
    // z_sf: S[t][s] = Ks[t].Qf[s]  -> A=Qf, B=Ks (both native bf16)
    f32x4 asf = __builtin_amdgcn_mfma_f32_16x16x32_bf16(fQf, fKs, zf, 0, 0, 0);
    // z_ss: S[t][s] = Qs[t].Ks[s]  -> A=Ks, B=Qs(hi,lo)
    f32x4 ass = __builtin_amdgcn_mfma_f32_16x16x32_bf16(fKs, fQsh, zf, 0, 0, 0);
    ass = __builtin_amdgcn_mfma_f32_16x16x32_bf16(fKs, fQsl, ass, 0, 0, 0);

    // ---- V B-fragments from LDS ----
    __syncthreads();
    s16x8 vbf0 = load_vfrag(sVf, wave * 32 + r16,      g);
    s16x8 vbf1 = load_vfrag(sVf, wave * 32 + 16 + r16, g);
    s16x8 vbs0 = load_vfrag(sVs, wave * 32 + r16,      g);
    s16x8 vbs1 = load_vfrag(sVs, wave * 32 + 16 + r16, g);

    // ---- softmax + ctx + store, per score matrix ----
    s16x8 ph, pl;
    softmax_swapped(aff, g, ph, pl);
    ctx_store(ph, pl, vbf0, vbf1, c0, abase, g, r16);
    softmax_swapped(afs, g, ph, pl);
    ctx_store(ph, pl, vbf0, vbf1, c1, abase, g, r16);
    softmax_swapped(asf, g, ph, pl);
    ctx_store(ph, pl, vbs0, vbs1, c2, abase, g, r16);
    softmax_swapped(ass, g, ph, pl);
    ctx_store(ph, pl, vbs0, vbs1, c3, abase, g, r16);
}

// ---------------- host launcher ----------------
extern "C" void kernel_launch(void* const* d_in, const int* in_sizes, int n_in,
                              void* d_out, int out_size, void* d_ws, size_t ws_size,
                              hipStream_t stream) {
    (void)in_sizes; (void)n_in; (void)out_size; (void)ws_size;

    const float* flow_q  = (const float*)d_in[0];
    const float* flow_k  = (const float*)d_in[1];
    const float* flow_v  = (const float*)d_in[2];
    const float* speed_q = (const float*)d_in[3];
    const float* speed_k = (const float*)d_in[4];
    const float* speed_v = (const float*)d_in[5];
    const float* w_fq  = (const float*)d_in[6];
    const float* w_fk  = (const float*)d_in[7];
    const float* w_fv  = (const float*)d_in[8];
    const float* w_sq  = (const float*)d_in[9];
    const float* w_sk  = (const float*)d_in[10];
    const float* w_sv  = (const float*)d_in[11];
    const float* w_out = (const float*)d_in[12];
    const float* b_out = (const float*)d_in[13];
    const float* kj    = (const float*)d_in[14];
    const float* vf    = (const float*)d_in[15];

    char* ws = (char*)d_ws;
    size_t off = 0;
    auto alloc = [&](size_t bytes) -> void* {
        void* p = ws + off;
        off += (bytes + 255) & ~(size_t)255;
        return p;
    };
    ushort* Wh = (ushort*)alloc(7 * 65536 * 2);   // bf16 hi for 7 weight mats
    ushort* Wl = (ushort*)alloc(7 * 65536 * 2);   // bf16 lo residual
    ushort* Qf = (ushort*)alloc(NEl * 2);
    float*  Kf = (float*) alloc(NEl * 4);         // fp32: sensitive (z_fs logits)
    ushort* Vf = (ushort*)alloc(NEl * 2);
    float*  Qs = (float*) alloc(NEl * 4);         // fp32: feeds physics transform
    ushort* Ks = (ushort*)alloc(NEl * 2);
    ushort* Vs = (ushort*)alloc(NEl * 2);
    ushort* c0 = (ushort*)alloc(NEl * 2);
    ushort* c1 = (ushort*)alloc(NEl * 2);
    ushort* c2 = (ushort*)alloc(NEl * 2);
    ushort* c3 = (ushort*)alloc(NEl * 2);

    float* out = (float*)d_out;

    // 0) convert weights once per launch
    WPtrs wp;
    wp.src[0] = w_fq; wp.src[1] = w_fk; wp.src[2] = w_fv; wp.src[3] = w_sq;
    wp.src[4] = w_sk; wp.src[5] = w_sv; wp.src[6] = w_out;
    wconv_k<<<dim3(7 * 65536 / 256), 256, 0, stream>>>(wp, Wh, Wl);

    // 1a) 4 insensitive projections: 1-pass bf16, bf16 out
    GPtrs p1;
    p1.A[0] = flow_q;  p1.Wh[0] = Wh + 0 * 65536; p1.Wl[0] = Wl + 0 * 65536; p1.Y[0] = Qf;
    p1.A[1] = flow_v;  p1.Wh[1] = Wh + 2 * 65536; p1.Wl[1] = Wl + 2 * 65536; p1.Y[1] = Vf;
    p1.A[2] = speed_k; p1.Wh[2] = Wh + 4 * 65536; p1.Wl[2] = Wl + 4 * 65536; p1.Y[2] = Ks;
    p1.A[3] = speed_v; p1.Wh[3] = Wh + 5 * 65536; p1.Wl[3] = Wl + 5 * 65536; p1.Y[3] = Vs;
    gemm_k<false, false, true, false><<<dim3(Mrows / 64, 4), 256, 0, stream>>>(p1, nullptr);

    // 1b) 2 sensitive projections: split bf16x3 (~fp32), fp32 out
    GPtrs p2;
    p2.A[0] = flow_k;  p2.Wh[0] = Wh + 1 * 65536; p2.Wl[0] = Wl + 1 * 65536; p2.Y[0] = Kf;
    p2.A[1] = speed_q; p2.Wh[1] = Wh + 3 * 65536; p2.Wl[1] = Wl + 3 * 65536; p2.Y[1] = Qs;
    p2.A[2] = flow_k;  p2.Wh[2] = Wh + 1 * 65536; p2.Wl[2] = Wl + 1 * 65536; p2.Y[2] = Kf; // unused
    p2.A[3] = flow_k;  p2.Wh[3] = Wh + 1 * 65536; p2.Wl[3] = Wl + 1 * 65536; p2.Y[3] = Kf; // unused
    gemm_k<true, false, false, false><<<dim3(Mrows / 64, 2), 256, 0, stream>>>(p2, nullptr);

    // 2) attention: MFMA, one wave per (b,n,h); 8 heads per block
    attn_k<<<dim3(Bn * Nn), 512, 0, stream>>>(Qf, Kf, Vf, Qs, Ks, Vs, kj, vf, c0, c1, c2, c3);

    // 3) out projections: bf16 in, fp32 out + bias
    GPtrs p3;
    p3.A[0] = c0; p3.Wh[0] = Wh + 6 * 65536; p3.Wl[0] = Wl + 6 * 65536; p3.Y[0] = out;
    p3.A[1] = c1; p3.Wh[1] = Wh + 6 * 65536; p3.Wl[1] = Wl + 6 * 65536; p3.Y[1] = out + NEl;
    p3.A[2] = c2; p3.Wh[2] = Wh + 6 * 65536; p3.Wl[2] = Wl + 6 * 65536; p3.Y[2] = out + 2 * NEl;
    p3.A[3] = c3; p3.Wh[3] = Wh + 6 * 65536; p3.Wl[3] = Wl + 6 * 65536; p3.Y[3] = out + 3 * NEl;
    gemm_k<false, true, false, true><<<dim3(Mrows / 64, 4), 256, 0, stream>>>(p3, b_out);
}

// Round 2
// 601.878 us; speedup vs baseline: 1.2624x; 1.0367x over previous
//
#include <hip/hip_runtime.h>

// ---- problem constants ----
#define Bn 4
#define Nn 1024
#define Tn 12
#define Cn 256
#define Hn 8
#define DKn 32
#define Mrows 49152            // B*N*T
#define NEl 12582912LL         // B*N*T*C
#define SCALE_ 0.17677669529663687f  // 1/sqrt(32)

typedef __attribute__((ext_vector_type(4))) float f32x4;
typedef __attribute__((ext_vector_type(8))) short s16x8;
typedef __attribute__((ext_vector_type(4))) short s16x4;

__device__ __forceinline__ ushort f2bfu(float x) {       // fp32 -> bf16 (RNE)
    unsigned u = __builtin_bit_cast(unsigned, x);
    u += 0x7fffu + ((u >> 16) & 1u);
    return (ushort)(u >> 16);
}
__device__ __forceinline__ float bfu2f(ushort h) {
    return __builtin_bit_cast(float, ((unsigned)h) << 16);
}

// async global->LDS, 16B per lane; dest = wave-uniform base + lane*16
__device__ __forceinline__ void gld_lds16(const void* g, void* l) {
    __builtin_amdgcn_global_load_lds(
        (const __attribute__((address_space(1))) unsigned*)g,
        (__attribute__((address_space(3))) unsigned*)l, 16, 0, 0);
}

// ---------------- weight pre-conversion: fp32 -> bf16 hi + lo residual ----------------
struct WPtrs { const float* src[7]; };

__global__ __launch_bounds__(256)
void wconv_k(WPtrs w, ushort* __restrict__ Wh, ushort* __restrict__ Wl) {
    int idx = blockIdx.x * 256 + threadIdx.x;   // 7*65536 total, exact grid
    int which = idx >> 16, pos = idx & 65535;
    float x = w.src[which][pos];
    ushort h = f2bfu(x);
    Wh[idx] = h;
    Wl[idx] = f2bfu(x - bfu2f(h));
}

// ---------------- batched GEMM: Y[m,o] = sum_c A[m,c] * W[o,c] (+bias) ----------------
// BM=128, BN=256(full), BK=32; 512 threads = 8 waves (2M x 4N), wave = 64x64 output.
// Double-buffered LDS, ONE barrier per K-step: stage(next) || compute(cur).
// W (and A when bf16) staged via global_load_lds w=16; LDS XOR-swizzled (T2) with
// pre-swizzled GLOBAL source so the linear lane*16 dest still lands right (rule #21).
// swizzle: byte' = (r*64 + cb) ^ (((r>>1)&3)<<4)  -- 16B-granular, read 2-way (free).
struct GPtrs {
    const void*   A[4];
    const ushort* Wh[4];
    const ushort* Wl[4];
    void*         Y[4];
};

template<bool SPLIT, bool IN_BF16, bool OUT_BF16, bool BIAS>
__device__ __forceinline__ void gemm_body(GPtrs p, const float* __restrict__ bias) {
    const int bt   = blockIdx.y;
    const int bm   = blockIdx.x * 128;
    const int tid  = threadIdx.x;
    const int lane = tid & 63;
    const int wave = tid >> 6;      // 0..7
    const int wm   = wave >> 2;     // 0..1  (row half)
    const int wn   = wave & 3;      // 0..3  (col quarter)
    const int r16  = lane & 15;
    const int cbf  = (lane >> 4) * 16;   // frag k-byte offset (0,16,32,48)

    constexpr int ASZ = 128 * 32;   // shorts, 8 KB
    constexpr int BSZ = 256 * 32;   // shorts, 16 KB
    __shared__ ushort Ah[2][ASZ];
    __shared__ ushort Bh[2][BSZ];
    __shared__ ushort Al[SPLIT ? 2 : 1][SPLIT ? ASZ : 8];
    __shared__ ushort Bl[SPLIT ? 2 : 1][SPLIT ? BSZ : 8];

    f32x4 acc[4][4];
#pragma unroll
    for (int i = 0; i < 4; i++)
#pragma unroll
        for (int j = 0; j < 4; j++)
            acc[i][j] = (f32x4){0.f, 0.f, 0.f, 0.f};

    // ---- staging ----
    auto stage = [&](int buf, int k0) {
        // B tile 256x32 via global_load_lds: 2 chunks of 8 KB (8 waves x 1 KB)
#pragma unroll
        for (int c = 0; c < 2; ++c) {
            int ob = c * 8192 + wave * 1024 + lane * 16;   // dest byte (linear)
            int r  = ob >> 6;
            int cg = ((ob >> 4) & 3) ^ ((r >> 1) & 3);     // pre-swizzled source col-grp
            size_t goff = (size_t)r * 256 + k0 + cg * 8;
            void* ldst = (char*)&Bh[buf][0] + c * 8192 + wave * 1024;
            gld_lds16(p.Wh[bt] + goff, ldst);
            if constexpr (SPLIT) {
                void* ldstl = (char*)&Bl[buf][0] + c * 8192 + wave * 1024;
                gld_lds16(p.Wl[bt] + goff, ldstl);
            }
        }
        // A tile 128x32
        if constexpr (IN_BF16) {
            int ob = wave * 1024 + lane * 16;
            int r  = ob >> 6;
            int cg = ((ob >> 4) & 3) ^ ((r >> 1) & 3);
            const ushort* g = (const ushort*)p.A[bt] + (size_t)(bm + r) * 256 + k0 + cg * 8;
            void* ldst = (char*)&Ah[buf][0] + wave * 1024;
            gld_lds16(g, ldst);
        } else {
            int r  = tid >> 2;                       // 0..127
            int cg = (tid & 3) ^ ((r >> 1) & 3);
            const float* g = (const float*)p.A[bt] + (size_t)(bm + r) * 256 + k0 + cg * 8;
            f32x4 v0 = *(const f32x4*)g;
            f32x4 v1 = *(const f32x4*)(g + 4);
            s16x8 hi, lo;
#pragma unroll
            for (int j = 0; j < 8; j++) {
                float x = (j < 4) ? v0[j] : v1[j - 4];
                ushort hb = f2bfu(x);
                hi[j] = (short)hb;
                if constexpr (SPLIT) lo[j] = (short)f2bfu(x - bfu2f(hb));
            }
            // dest tid*16 == swizzled address of (r, cg) by construction
            *(s16x8*)((char*)&Ah[buf][0] + tid * 16) = hi;
            if constexpr (SPLIT) *(s16x8*)((char*)&Al[buf][0] + tid * 16) = lo;
        }
    };

    auto compute = [&](int buf) {
        s16x8 a[4], al[4];
#pragma unroll
        for (int mi = 0; mi < 4; mi++) {
            int R   = wm * 64 + mi * 16 + r16;
            int off = (R * 64 + cbf) ^ (((R >> 1) & 3) << 4);
            a[mi] = *(const s16x8*)((const char*)&Ah[buf][0] + off);
            if constexpr (SPLIT) al[mi] = *(const s16x8*)((const char*)&Al[buf][0] + off);
        }
#pragma unroll
        for (int ni = 0; ni < 4; ni++) {
            int R   = wn * 64 + ni * 16 + r16;
            int off = (R * 64 + cbf) ^ (((R >> 1) & 3) << 4);
            s16x8 b = *(const s16x8*)((const char*)&Bh[buf][0] + off);
            s16x8 bl;
            if constexpr (SPLIT) bl = *(const s16x8*)((const char*)&Bl[buf][0] + off);
#pragma unroll
            for (int mi = 0; mi < 4; mi++) {
                acc[mi][ni] = __builtin_amdgcn_mfma_f32_16x16x32_bf16(a[mi], b, acc[mi][ni], 0, 0, 0);
                if constexpr (SPLIT) {
                    acc[mi][ni] = __builtin_amdgcn_mfma_f32_16x16x32_bf16(al[mi], b,  acc[mi][ni], 0, 0, 0);
                    acc[mi][ni] = __builtin_amdgcn_mfma_f32_16x16x32_bf16(a[mi],  bl, acc[mi][ni], 0, 0, 0);
                }
            }
        }
    };

    // ---- pipeline: one barrier per K-step ----
    stage(0, 0);
    __syncthreads();                       // vmcnt(0)+lgkmcnt(0) drain: buf0 ready
#pragma unroll
    for (int ks = 0; ks < 8; ++ks) {
        if (ks < 7) stage((ks + 1) & 1, (ks + 1) * 32);   // loads fly under MFMAs
        compute(ks & 1);
        __syncthreads();                   // drains next-tile loads + cur reads
    }

    // ---- epilogue: C/D layout col=lane&15, row=(lane>>4)*4+reg ----
#pragma unroll
    for (int mi = 0; mi < 4; mi++) {
#pragma unroll
        for (int ni = 0; ni < 4; ni++) {
            int col  = wn * 64 + ni * 16 + r16;
            int row0 = bm + wm * 64 + mi * 16 + (lane >> 4) * 4;
            float bv = BIAS ? bias[col] : 0.f;
#pragma unroll
            for (int rg = 0; rg < 4; rg++) {
                float v = acc[mi][ni][rg] + bv;
                size_t idx = (size_t)(row0 + rg) * 256 + col;
                if constexpr (OUT_BF16) ((ushort*)p.Y[bt])[idx] = f2bfu(v);
                else                    ((float*)p.Y[bt])[idx]  = v;
            }
        }
    }
}

__global__ __launch_bounds__(512, 4)
void gemm_proj_k(GPtrs p) { gemm_body<false, false, true, false>(p, nullptr); }

__global__ __launch_bounds__(512, 2)
void gemm_split_k(GPtrs p) { gemm_body<true, false, false, false>(p, nullptr); }

__global__ __launch_bounds__(512, 4)
void gemm_out_k(GPtrs p, const float* __restrict__ bias) {
    gemm_body<false, true, false, true>(p, bias);
}

// ---------------- MFMA attention ----------------
// One wave per (b,n,h). Block = 512 threads = 8 waves = all 8 heads of one (b,n).
// (unchanged from round 1 — see prior analysis)

#define VSTR 268   // shorts; row stride

__device__ __forceinline__ s16x8 zero8() { s16x8 z = {0,0,0,0,0,0,0,0}; return z; }

__device__ __forceinline__ void split8(f32x4 a, f32x4 b, s16x8& hi, s16x8& lo) {
#pragma unroll
    for (int j = 0; j < 8; j++) {
        float x = (j < 4) ? a[j] : b[j - 4];
        ushort h = f2bfu(x);
        hi[j] = (short)h;
        lo[j] = (short)f2bfu(x - bfu2f(h));
    }
}

__device__ __forceinline__ void softmax_swapped(f32x4 acc, int g, s16x8& ph, s16x8& pl) {
    float x0 = acc[0] * SCALE_, x1 = acc[1] * SCALE_;
    float x2 = acc[2] * SCALE_, x3 = acc[3] * SCALE_;
    float m = fmaxf(fmaxf(x0, x1), fmaxf(x2, x3));
    m = fmaxf(m, __shfl_xor(m, 16));
    m = fmaxf(m, __shfl_xor(m, 32));
    float e0 = expf(x0 - m), e1 = expf(x1 - m), e2 = expf(x2 - m), e3 = expf(x3 - m);
    if (g == 3) { e0 = 0.f; e1 = 0.f; e2 = 0.f; e3 = 0.f; }   // s=12..15 masked
    float s = e0 + e1 + e2 + e3;
    s += __shfl_xor(s, 16);
    s += __shfl_xor(s, 32);
    float inv = 1.f / s;
    float p0 = e0 * inv, p1 = e1 * inv, p2 = e2 * inv, p3 = e3 * inv;
    float q0 = __shfl_down(p0, 16), q1 = __shfl_down(p1, 16);
    float q2 = __shfl_down(p2, 16), q3 = __shfl_down(p3, 16);
    float w[8];
    if (g == 0) { w[0]=p0; w[1]=p1; w[2]=p2; w[3]=p3; w[4]=q0; w[5]=q1; w[6]=q2; w[7]=q3; }
    else if (g == 1) { w[0]=q0; w[1]=q1; w[2]=q2; w[3]=q3; w[4]=0.f; w[5]=0.f; w[6]=0.f; w[7]=0.f; }
    else { w[0]=0.f; w[1]=0.f; w[2]=0.f; w[3]=0.f; w[4]=0.f; w[5]=0.f; w[6]=0.f; w[7]=0.f; }
#pragma unroll
    for (int j = 0; j < 8; j++) {
        ushort h = f2bfu(w[j]);
        ph[j] = (short)h;
        pl[j] = (short)f2bfu(w[j] - bfu2f(h));
    }
}

__device__ __forceinline__ s16x8 load_vfrag(const ushort* sV, int col, int g) {
    s16x8 v = zero8();
    if (g < 2) {
#pragma unroll
        for (int j = 0; j < 8; j++) {
            int s = 8 * g + j;
            if (s < 12) v[j] = (short)sV[s * VSTR + col];
        }
    }
    return v;
}

__device__ __forceinline__ void ctx_store(s16x8 ph, s16x8 pl, s16x8 vb0, s16x8 vb1,
                                          ushort* __restrict__ dst, size_t abase,
                                          int g, int r16) {
    f32x4 zf = {0.f, 0.f, 0.f, 0.f};
    f32x4 o0 = __builtin_amdgcn_mfma_f32_16x16x32_bf16(ph, vb0, zf, 0, 0, 0);
    o0 = __builtin_amdgcn_mfma_f32_16x16x32_bf16(pl, vb0, o0, 0, 0, 0);
    f32x4 o1 = __builtin_amdgcn_mfma_f32_16x16x32_bf16(ph, vb1, zf, 0, 0, 0);
    o1 = __builtin_amdgcn_mfma_f32_16x16x32_bf16(pl, vb1, o1, 0, 0, 0);
    if (g < 3) {
#pragma unroll
        for (int rg = 0; rg < 4; rg++) {
            size_t row = (size_t)(4 * g + rg) * Cn;
            dst[abase + row + r16]      = f2bfu(o0[rg]);
            dst[abase + row + 16 + r16] = f2bfu(o1[rg]);
        }
    }
}

__global__ __launch_bounds__(512)
void attn_k(const ushort* __restrict__ Qf, const float* __restrict__ Kf,
            const ushort* __restrict__ Vf, const float* __restrict__ Qs,
            const ushort* __restrict__ Ks, const ushort* __restrict__ Vs,
            const float* __restrict__ kj, const float* __restrict__ vf_fs,
            ushort* __restrict__ c0, ushort* __restrict__ c1,
            ushort* __restrict__ c2, ushort* __restrict__ c3)
{
    const int bn   = blockIdx.x;          // b*N + n
    const int tid  = threadIdx.x;
    const int wave = tid >> 6;            // head h = wave
    const int lane = tid & 63;
    const int g    = lane >> 4;           // k-group 0..3
    const int r16  = lane & 15;

    __shared__ ushort sVf[12 * VSTR];
    __shared__ ushort sVs[12 * VSTR];

    if (tid < 384) {
        int t = tid >> 5;                 // 0..11
        int c = (tid & 31) * 8;           // 0..248
        size_t gb = (size_t)bn * (Tn * Cn) + (size_t)t * Cn + c;
        s16x8 vf8 = *(const s16x8*)(Vf + gb);
        s16x8 vs8 = *(const s16x8*)(Vs + gb);
        s16x4 a0 = {vf8[0], vf8[1], vf8[2], vf8[3]};
        s16x4 a1 = {vf8[4], vf8[5], vf8[6], vf8[7]};
        s16x4 b0 = {vs8[0], vs8[1], vs8[2], vs8[3]};
        s16x4 b1 = {vs8[4], vs8[5], vs8[6], vs8[7]};
        *(s16x4*)&sVf[t * VSTR + c]     = a0;
        *(s16x4*)&sVf[t * VSTR + c + 4] = a1;
        *(s16x4*)&sVs[t * VSTR + c]     = b0;
        *(s16x4*)&sVs[t * VSTR + c + 4] = b1;
    }

    const int  t    = r16;
    const bool tv   = t < 12;
    const int  d0   = g * 8;
    const size_t abase = (size_t)bn * (Tn * Cn) + (size_t)wave * DKn;
    const size_t rb    = abase + (size_t)t * Cn + d0;

    f32x4 z4 = {0.f, 0.f, 0.f, 0.f};
    s16x8 fQf = tv ? *(const s16x8*)(Qf + rb) : zero8();
    s16x8 fKs = tv ? *(const s16x8*)(Ks + rb) : zero8();

    f32x4 kfa = tv ? *(const f32x4*)(Kf + rb)     : z4;
    f32x4 kfb = tv ? *(const f32x4*)(Kf + rb + 4) : z4;
    f32x4 qsa = tv ? *(const f32x4*)(Qs + rb)     : z4;
    f32x4 qsb = tv ? *(const f32x4*)(Qs + rb + 4) : z4;

    s16x8 fKfh, fKfl, fQsh, fQsl;
    split8(kfa, kfb, fKfh, fKfl);
    split8(qsa, qsb, fQsh, fQsl);

    float kjt  = tv ? kj[t]    : 0.f;
    float vft  = tv ? vf_fs[t] : 0.f;
    float invv = 1.f / (vft + 1e-5f);
    f32x4 qfa, qfb;
#pragma unroll
    for (int j = 0; j < 4; j++) {
        float qa = qsa[j], qb = qsb[j];
        qfa[j] = kjt * (qa - qa * qa * invv);
        qfb[j] = kjt * (qb - qb * qb * invv);
    }
    s16x8 fqfh, fqfl;
    split8(qfa, qfb, fqfh, fqfl);

    f32x4 zf = {0.f, 0.f, 0.f, 0.f};
    f32x4 aff = __builtin_amdgcn_mfma_f32_16x16x32_bf16(fKfh, fQf, zf, 0, 0, 0);
    aff = __builtin_amdgcn_mfma_f32_16x16x32_bf16(fKfl, fQf, aff, 0, 0, 0);
    f32x4 afs = __builtin_amdgcn_mfma_f32_16x16x32_bf16(fqfh, fKfh, zf, 0, 0, 0);
    afs = __builtin_amdgcn_mfma_f32_16x16x32_bf16(fqfl, fKfh, afs, 0, 0, 0);
    afs = __builtin_amdgcn_mfma_f32_16x16x32_bf16(fqfh, fKfl, afs, 0, 0, 0);
    afs = __builtin_amdgcn_mfma_f32_16x16x32_bf16(fqfl, fKfl, afs, 0, 0, 0);
    f32x4 asf = __builtin_amdgcn_mfma_f32_16x16x32_bf16(fQf, fKs, zf, 0, 0, 0);
    f32x4 ass = __builtin_amdgcn_mfma_f32_16x16x32_bf16(fKs, fQsh, zf, 0, 0, 0);
    ass = __builtin_amdgcn_mfma_f32_16x16x32_bf16(fKs, fQsl, ass, 0, 0, 0);

    __syncthreads();
    s16x8 vbf0 = load_vfrag(sVf, wave * 32 + r16,      g);
    s16x8 vbf1 = load_vfrag(sVf, wave * 32 + 16 + r16, g);
    s16x8 vbs0 = load_vfrag(sVs, wave * 32 + r16,      g);
    s16x8 vbs1 = load_vfrag(sVs, wave * 32 + 16 + r16, g);

    s16x8 ph, pl;
    softmax_swapped(aff, g, ph, pl);
    ctx_store(ph, pl, vbf0, vbf1, c0, abase, g, r16);
    softmax_swapped(afs, g, ph, pl);
    ctx_store(ph, pl, vbf0, vbf1, c1, abase, g, r16);
    softmax_swapped(asf, g, ph, pl);
    ctx_store(ph, pl, vbs0, vbs1, c2, abase, g, r16);
    softmax_swapped(ass, g, ph, pl);
    ctx_store(ph, pl, vbs0, vbs1, c3, abase, g, r16);
}

// ---------------- host launcher ----------------
extern "C" void kernel_launch(void* const* d_in, const int* in_sizes, int n_in,
                              void* d_out, int out_size, void* d_ws, size_t ws_size,
                              hipStream_t stream) {
    (void)in_sizes; (void)n_in; (void)out_size; (void)ws_size;

    const float* flow_q  = (const float*)d_in[0];
    const float* flow_k  = (const float*)d_in[1];
    const float* flow_v  = (const float*)d_in[2];
    const float* speed_q = (const float*)d_in[3];
    const float* speed_k = (const float*)d_in[4];
    const float* speed_v = (const float*)d_in[5];
    const float* w_fq  = (const float*)d_in[6];
    const float* w_fk  = (const float*)d_in[7];
    const float* w_fv  = (const float*)d_in[8];
    const float* w_sq  = (const float*)d_in[9];
    const float* w_sk  = (const float*)d_in[10];
    const float* w_sv  = (const float*)d_in[11];
    const float* w_out = (const float*)d_in[12];
    const float* b_out = (const float*)d_in[13];
    const float* kj    = (const float*)d_in[14];
    const float* vf    = (const float*)d_in[15];

    char* ws = (char*)d_ws;
    size_t off = 0;
    auto alloc = [&](size_t bytes) -> void* {
        void* p = ws + off;
        off += (bytes + 255) & ~(size_t)255;
        return p;
    };
    ushort* Wh = (ushort*)alloc(7 * 65536 * 2);   // bf16 hi for 7 weight mats
    ushort* Wl = (ushort*)alloc(7 * 65536 * 2);   // bf16 lo residual
    ushort* Qf = (ushort*)alloc(NEl * 2);
    float*  Kf = (float*) alloc(NEl * 4);         // fp32: sensitive (z_fs logits)
    ushort* Vf = (ushort*)alloc(NEl * 2);
    float*  Qs = (float*) alloc(NEl * 4);         // fp32: feeds physics transform
    ushort* Ks = (ushort*)alloc(NEl * 2);
    ushort* Vs = (ushort*)alloc(NEl * 2);
    ushort* c0 = (ushort*)alloc(NEl * 2);
    ushort* c1 = (ushort*)alloc(NEl * 2);
    ushort* c2 = (ushort*)alloc(NEl * 2);
    ushort* c3 = (ushort*)alloc(NEl * 2);

    float* out = (float*)d_out;

    // 0) convert weights once per launch
    WPtrs wp;
    wp.src[0] = w_fq; wp.src[1] = w_fk; wp.src[2] = w_fv; wp.src[3] = w_sq;
    wp.src[4] = w_sk; wp.src[5] = w_sv; wp.src[6] = w_out;
    wconv_k<<<dim3(7 * 65536 / 256), 256, 0, stream>>>(wp, Wh, Wl);

    // 1a) 4 insensitive projections: 1-pass bf16, bf16 out
    GPtrs p1;
    p1.A[0] = flow_q;  p1.Wh[0] = Wh + 0 * 65536; p1.Wl[0] = Wl + 0 * 65536; p1.Y[0] = Qf;
    p1.A[1] = flow_v;  p1.Wh[1] = Wh + 2 * 65536; p1.Wl[1] = Wl + 2 * 65536; p1.Y[1] = Vf;
    p1.A[2] = speed_k; p1.Wh[2] = Wh + 4 * 65536; p1.Wl[2] = Wl + 4 * 65536; p1.Y[2] = Ks;
    p1.A[3] = speed_v; p1.Wh[3] = Wh + 5 * 65536; p1.Wl[3] = Wl + 5 * 65536; p1.Y[3] = Vs;
    gemm_proj_k<<<dim3(Mrows / 128, 4), 512, 0, stream>>>(p1);

    // 1b) 2 sensitive projections: split bf16x3 (~fp32), fp32 out
    GPtrs p2;
    p2.A[0] = flow_k;  p2.Wh[0] = Wh + 1 * 65536; p2.Wl[0] = Wl + 1 * 65536; p2.Y[0] = Kf;
    p2.A[1] = speed_q; p2.Wh[1] = Wh + 3 * 65536; p2.Wl[1] = Wl + 3 * 65536; p2.Y[1] = Qs;
    p2.A[2] = flow_k;  p2.Wh[2] = Wh + 1 * 65536; p2.Wl[2] = Wl + 1 * 65536; p2.Y[2] = Kf; // unused
    p2.A[3] = flow_k;  p2.Wh[3] = Wh + 1 * 65536; p2.Wl[3] = Wl + 1 * 65536; p2.Y[3] = Kf; // unused
    gemm_split_k<<<dim3(Mrows / 128, 2), 512, 0, stream>>>(p2);

    // 2) attention: MFMA, one wave per (b,n,h); 8 heads per block
    attn_k<<<dim3(Bn * Nn), 512, 0, stream>>>(Qf, Kf, Vf, Qs, Ks, Vs, kj, vf, c0, c1, c2, c3);

    // 3) out projections: bf16 in, fp32 out + bias
    GPtrs p3;
    p3.A[0] = c0; p3.Wh[0] = Wh + 6 * 65536; p3.Wl[0] = Wl + 6 * 65536; p3.Y[0] = out;
    p3.A[1] = c1; p3.Wh[1] = Wh + 6 * 65536; p3.Wl[1] = Wl + 6 * 65536; p3.Y[1] = out + NEl;
    p3.A[2] = c2; p3.Wh[2] = Wh + 6 * 65536; p3.Wl[2] = Wl + 6 * 65536; p3.Y[2] = out + 2 * NEl;
    p3.A[3] = c3; p3.Wh[3] = Wh + 6 * 65536; p3.Wl[3] = Wl + 6 * 65536; p3.Y[3] = out + 3 * NEl;
    gemm_out_k<<<dim3(Mrows / 128, 4), 512, 0, stream>>>(p3, b_out);
}

// Round 3
// 593.973 us; speedup vs baseline: 1.2792x; 1.0133x over previous
//
#include <hip/hip_runtime.h>

// ---- problem constants ----
#define Bn 4
#define Nn 1024
#define Tn 12
#define Cn 256
#define Hn 8
#define DKn 32
#define Mrows 49152            // B*N*T
#define NEl 12582912LL         // B*N*T*C
#define SCALE_ 0.17677669529663687f  // 1/sqrt(32)

typedef __attribute__((ext_vector_type(4))) float f32x4;
typedef __attribute__((ext_vector_type(8))) short s16x8;
typedef __attribute__((ext_vector_type(4))) short s16x4;

__device__ __forceinline__ ushort f2bfu(float x) {       // fp32 -> bf16 (RNE)
    unsigned u = __builtin_bit_cast(unsigned, x);
    u += 0x7fffu + ((u >> 16) & 1u);
    return (ushort)(u >> 16);
}
__device__ __forceinline__ float bfu2f(ushort h) {
    return __builtin_bit_cast(float, ((unsigned)h) << 16);
}

// async global->LDS, 16B per lane; dest = wave-uniform base + lane*16
__device__ __forceinline__ void gld_lds16(const void* g, void* l) {
    __builtin_amdgcn_global_load_lds(
        (const __attribute__((address_space(1))) unsigned*)g,
        (__attribute__((address_space(3))) unsigned*)l, 16, 0, 0);
}

// ---------------- weight pre-conversion: fp32 -> bf16 hi + lo residual ----------------
struct WPtrs { const float* src[7]; };

__global__ __launch_bounds__(256)
void wconv_k(WPtrs w, ushort* __restrict__ Wh, ushort* __restrict__ Wl) {
    int idx = blockIdx.x * 256 + threadIdx.x;   // 7*65536 total, exact grid
    int which = idx >> 16, pos = idx & 65535;
    float x = w.src[which][pos];
    ushort h = f2bfu(x);
    Wh[idx] = h;
    Wl[idx] = f2bfu(x - bfu2f(h));
}

// ---------------- batched GEMM: Y[m,o] = sum_c A[m,c] * W[o,c] ----------------
// BM=128, BN=256(full), BK=32; 512 threads = 8 waves (2M x 4N), wave = 64x64 output.
// Double-buffered LDS, ONE barrier per K-step: stage(next) || compute(cur).
// W (and A when bf16) staged via global_load_lds w=16; LDS XOR-swizzled (T2) with
// pre-swizzled GLOBAL source so the linear lane*16 dest still lands right (rule #21).
struct GPtrs {
    const void*   A[4];
    const ushort* Wh[4];
    const ushort* Wl[4];
    void*         Y[4];
};

template<bool SPLIT, bool IN_BF16, bool OUT_BF16>
__device__ __forceinline__ void gemm_body(GPtrs p) {
    const int bt   = blockIdx.y;
    const int bm   = blockIdx.x * 128;
    const int tid  = threadIdx.x;
    const int lane = tid & 63;
    const int wave = tid >> 6;      // 0..7
    const int wm   = wave >> 2;     // 0..1  (row half)
    const int wn   = wave & 3;      // 0..3  (col quarter)
    const int r16  = lane & 15;
    const int cbf  = (lane >> 4) * 16;   // frag k-byte offset (0,16,32,48)

    constexpr int ASZ = 128 * 32;   // shorts, 8 KB
    constexpr int BSZ = 256 * 32;   // shorts, 16 KB
    __shared__ ushort Ah[2][ASZ];
    __shared__ ushort Bh[2][BSZ];
    __shared__ ushort Al[SPLIT ? 2 : 1][SPLIT ? ASZ : 8];
    __shared__ ushort Bl[SPLIT ? 2 : 1][SPLIT ? BSZ : 8];

    f32x4 acc[4][4];
#pragma unroll
    for (int i = 0; i < 4; i++)
#pragma unroll
        for (int j = 0; j < 4; j++)
            acc[i][j] = (f32x4){0.f, 0.f, 0.f, 0.f};

    auto stage = [&](int buf, int k0) {
#pragma unroll
        for (int c = 0; c < 2; ++c) {
            int ob = c * 8192 + wave * 1024 + lane * 16;   // dest byte (linear)
            int r  = ob >> 6;
            int cg = ((ob >> 4) & 3) ^ ((r >> 1) & 3);     // pre-swizzled source col-grp
            size_t goff = (size_t)r * 256 + k0 + cg * 8;
            void* ldst = (char*)&Bh[buf][0] + c * 8192 + wave * 1024;
            gld_lds16(p.Wh[bt] + goff, ldst);
            if constexpr (SPLIT) {
                void* ldstl = (char*)&Bl[buf][0] + c * 8192 + wave * 1024;
                gld_lds16(p.Wl[bt] + goff, ldstl);
            }
        }
        if constexpr (IN_BF16) {
            int ob = wave * 1024 + lane * 16;
            int r  = ob >> 6;
            int cg = ((ob >> 4) & 3) ^ ((r >> 1) & 3);
            const ushort* g = (const ushort*)p.A[bt] + (size_t)(bm + r) * 256 + k0 + cg * 8;
            void* ldst = (char*)&Ah[buf][0] + wave * 1024;
            gld_lds16(g, ldst);
        } else {
            int r  = tid >> 2;                       // 0..127
            int cg = (tid & 3) ^ ((r >> 1) & 3);
            const float* g = (const float*)p.A[bt] + (size_t)(bm + r) * 256 + k0 + cg * 8;
            f32x4 v0 = *(const f32x4*)g;
            f32x4 v1 = *(const f32x4*)(g + 4);
            s16x8 hi, lo;
#pragma unroll
            for (int j = 0; j < 8; j++) {
                float x = (j < 4) ? v0[j] : v1[j - 4];
                ushort hb = f2bfu(x);
                hi[j] = (short)hb;
                if constexpr (SPLIT) lo[j] = (short)f2bfu(x - bfu2f(hb));
            }
            *(s16x8*)((char*)&Ah[buf][0] + tid * 16) = hi;
            if constexpr (SPLIT) *(s16x8*)((char*)&Al[buf][0] + tid * 16) = lo;
        }
    };

    auto compute = [&](int buf) {
        s16x8 a[4], al[4];
#pragma unroll
        for (int mi = 0; mi < 4; mi++) {
            int R   = wm * 64 + mi * 16 + r16;
            int off = (R * 64 + cbf) ^ (((R >> 1) & 3) << 4);
            a[mi] = *(const s16x8*)((const char*)&Ah[buf][0] + off);
            if constexpr (SPLIT) al[mi] = *(const s16x8*)((const char*)&Al[buf][0] + off);
        }
#pragma unroll
        for (int ni = 0; ni < 4; ni++) {
            int R   = wn * 64 + ni * 16 + r16;
            int off = (R * 64 + cbf) ^ (((R >> 1) & 3) << 4);
            s16x8 b = *(const s16x8*)((const char*)&Bh[buf][0] + off);
            s16x8 bl;
            if constexpr (SPLIT) bl = *(const s16x8*)((const char*)&Bl[buf][0] + off);
#pragma unroll
            for (int mi = 0; mi < 4; mi++) {
                acc[mi][ni] = __builtin_amdgcn_mfma_f32_16x16x32_bf16(a[mi], b, acc[mi][ni], 0, 0, 0);
                if constexpr (SPLIT) {
                    acc[mi][ni] = __builtin_amdgcn_mfma_f32_16x16x32_bf16(al[mi], b,  acc[mi][ni], 0, 0, 0);
                    acc[mi][ni] = __builtin_amdgcn_mfma_f32_16x16x32_bf16(a[mi],  bl, acc[mi][ni], 0, 0, 0);
                }
            }
        }
    };

    stage(0, 0);
    __syncthreads();
#pragma unroll
    for (int ks = 0; ks < 8; ++ks) {
        if (ks < 7) stage((ks + 1) & 1, (ks + 1) * 32);   // loads fly under MFMAs
        compute(ks & 1);
        __syncthreads();
    }

#pragma unroll
    for (int mi = 0; mi < 4; mi++) {
#pragma unroll
        for (int ni = 0; ni < 4; ni++) {
            int col  = wn * 64 + ni * 16 + r16;
            int row0 = bm + wm * 64 + mi * 16 + (lane >> 4) * 4;
#pragma unroll
            for (int rg = 0; rg < 4; rg++) {
                float v = acc[mi][ni][rg];
                size_t idx = (size_t)(row0 + rg) * 256 + col;
                if constexpr (OUT_BF16) ((ushort*)p.Y[bt])[idx] = f2bfu(v);
                else                    ((float*)p.Y[bt])[idx]  = v;
            }
        }
    }
}

__global__ __launch_bounds__(512, 4)
void gemm_proj_k(GPtrs p) { gemm_body<false, false, true>(p); }

__global__ __launch_bounds__(512, 2)
void gemm_split_k(GPtrs p) { gemm_body<true, false, false>(p); }

// ---------------- fused MFMA attention + out-projection ----------------
// One block per (b,n): 512 threads = 8 waves.
// Phase 1 (wave = head): score mats via swapped MFMA + wave-parallel softmax +
//   ctx MFMA; ctx -> LDS bf16, XOR-swizzled (slot ^= t&7) for conflict-free reads.
// Phase 2 (wave = (mat, col-half)): ctx @ w_out^T + b_out, K=256 in 8 steps;
//   w_out tile (256x32) staged global->reg->LDS (T14), slot ^= (o>>1)&3 swizzle.
// LDS: [0,8192) ushorts = sVf/sVs (phase1) then w-tile (phase2); [8192,20480) ctx.

__device__ __forceinline__ s16x8 zero8() { s16x8 z = {0,0,0,0,0,0,0,0}; return z; }

__device__ __forceinline__ void split8(f32x4 a, f32x4 b, s16x8& hi, s16x8& lo) {
#pragma unroll
    for (int j = 0; j < 8; j++) {
        float x = (j < 4) ? a[j] : b[j - 4];
        ushort h = f2bfu(x);
        hi[j] = (short)h;
        lo[j] = (short)f2bfu(x - bfu2f(h));
    }
}

__device__ __forceinline__ void softmax_swapped(f32x4 acc, int g, s16x8& ph, s16x8& pl) {
    float x0 = acc[0] * SCALE_, x1 = acc[1] * SCALE_;
    float x2 = acc[2] * SCALE_, x3 = acc[3] * SCALE_;
    float m = fmaxf(fmaxf(x0, x1), fmaxf(x2, x3));
    m = fmaxf(m, __shfl_xor(m, 16));
    m = fmaxf(m, __shfl_xor(m, 32));
    float e0 = expf(x0 - m), e1 = expf(x1 - m), e2 = expf(x2 - m), e3 = expf(x3 - m);
    if (g == 3) { e0 = 0.f; e1 = 0.f; e2 = 0.f; e3 = 0.f; }   // s=12..15 masked
    float s = e0 + e1 + e2 + e3;
    s += __shfl_xor(s, 16);
    s += __shfl_xor(s, 32);
    float inv = 1.f / s;
    float p0 = e0 * inv, p1 = e1 * inv, p2 = e2 * inv, p3 = e3 * inv;
    float q0 = __shfl_down(p0, 16), q1 = __shfl_down(p1, 16);
    float q2 = __shfl_down(p2, 16), q3 = __shfl_down(p3, 16);
    float w[8];
    if (g == 0) { w[0]=p0; w[1]=p1; w[2]=p2; w[3]=p3; w[4]=q0; w[5]=q1; w[6]=q2; w[7]=q3; }
    else if (g == 1) { w[0]=q0; w[1]=q1; w[2]=q2; w[3]=q3; w[4]=0.f; w[5]=0.f; w[6]=0.f; w[7]=0.f; }
    else { w[0]=0.f; w[1]=0.f; w[2]=0.f; w[3]=0.f; w[4]=0.f; w[5]=0.f; w[6]=0.f; w[7]=0.f; }
#pragma unroll
    for (int j = 0; j < 8; j++) {
        ushort h = f2bfu(w[j]);
        ph[j] = (short)h;
        pl[j] = (short)f2bfu(w[j] - bfu2f(h));
    }
}

#define VSTR 268   // shorts; V row stride (phase 1)

__device__ __forceinline__ s16x8 load_vfrag(const ushort* sV, int col, int g) {
    s16x8 v = zero8();
    if (g < 2) {
#pragma unroll
        for (int j = 0; j < 8; j++) {
            int s = 8 * g + j;
            if (s < 12) v[j] = (short)sV[s * VSTR + col];
        }
    }
    return v;
}

// ctx MFMA + swizzled LDS store: ctx[mat][t][head*32 + {r16, 16+r16}]
__device__ __forceinline__ void ctx_to_lds(ushort* smem, s16x8 ph, s16x8 pl,
                                           s16x8 vb0, s16x8 vb1,
                                           int mat, int head, int g, int r16) {
    f32x4 zf = {0.f, 0.f, 0.f, 0.f};
    f32x4 o0 = __builtin_amdgcn_mfma_f32_16x16x32_bf16(ph, vb0, zf, 0, 0, 0);
    o0 = __builtin_amdgcn_mfma_f32_16x16x32_bf16(pl, vb0, o0, 0, 0, 0);
    f32x4 o1 = __builtin_amdgcn_mfma_f32_16x16x32_bf16(ph, vb1, zf, 0, 0, 0);
    o1 = __builtin_amdgcn_mfma_f32_16x16x32_bf16(pl, vb1, o1, 0, 0, 0);
    if (g < 3) {
        int grp = head * 4 + (r16 >> 3);
        int c7  = r16 & 7;
#pragma unroll
        for (int rg = 0; rg < 4; rg++) {
            int t = 4 * g + rg;
            int base = 8192 + mat * 3072 + t * 256 + c7;
            smem[base + (((grp    ) ^ (t & 7)) << 3)] = f2bfu(o0[rg]);
            smem[base + (((grp + 2) ^ (t & 7)) << 3)] = f2bfu(o1[rg]);
        }
    }
}

__global__ __launch_bounds__(512)
void attn_out_k(const ushort* __restrict__ Qf, const float* __restrict__ Kf,
                const ushort* __restrict__ Vf, const float* __restrict__ Qs,
                const ushort* __restrict__ Ks, const ushort* __restrict__ Vs,
                const float* __restrict__ kj, const float* __restrict__ vf_fs,
                const ushort* __restrict__ Wo, const float* __restrict__ b_out,
                float* __restrict__ out)
{
    const int bn   = blockIdx.x;          // b*N + n
    const int tid  = threadIdx.x;
    const int wave = tid >> 6;            // phase1: head; phase2: (mat, half)
    const int lane = tid & 63;
    const int g    = lane >> 4;           // k-group 0..3
    const int r16  = lane & 15;

    __shared__ ushort smem[20480];        // 40 KB

    // ---- prefetch w_out tile for ks=0 (consumed in phase 2) ----
    const int wo_row  = tid >> 1;                       // 0..255
    const int wo_cg0  = (tid & 1) * 2;                  // 0 or 2
    const int wo_swz  = (wo_row >> 1) & 3;
    const int wslot0  = wo_cg0 ^ wo_swz;
    const int wslot1  = (wo_cg0 + 1) ^ wo_swz;
    const ushort* wgb = Wo + (size_t)wo_row * 256 + wo_cg0 * 8;
    s16x8 wa = *(const s16x8*)(wgb);
    s16x8 wb = *(const s16x8*)(wgb + 8);

    // ---- phase 1: stage Vf, Vs rows into LDS region0, coalesced ----
    ushort* sVf = smem;
    ushort* sVs = smem + 12 * VSTR;
    if (tid < 384) {
        int t = tid >> 5;                 // 0..11
        int c = (tid & 31) * 8;           // 0..248
        size_t gb = (size_t)bn * (Tn * Cn) + (size_t)t * Cn + c;
        s16x8 vf8 = *(const s16x8*)(Vf + gb);
        s16x8 vs8 = *(const s16x8*)(Vs + gb);
        s16x4 a0 = {vf8[0], vf8[1], vf8[2], vf8[3]};
        s16x4 a1 = {vf8[4], vf8[5], vf8[6], vf8[7]};
        s16x4 b0 = {vs8[0], vs8[1], vs8[2], vs8[3]};
        s16x4 b1 = {vs8[4], vs8[5], vs8[6], vs8[7]};
        *(s16x4*)&sVf[t * VSTR + c]     = a0;
        *(s16x4*)&sVf[t * VSTR + c + 4] = a1;
        *(s16x4*)&sVs[t * VSTR + c]     = b0;
        *(s16x4*)&sVs[t * VSTR + c + 4] = b1;
    }

    const int  t    = r16;
    const bool tv   = t < 12;
    const int  d0   = g * 8;
    const size_t abase = (size_t)bn * (Tn * Cn) + (size_t)wave * DKn;
    const size_t rb    = abase + (size_t)t * Cn + d0;

    f32x4 z4 = {0.f, 0.f, 0.f, 0.f};
    s16x8 fQf = tv ? *(const s16x8*)(Qf + rb) : zero8();
    s16x8 fKs = tv ? *(const s16x8*)(Ks + rb) : zero8();

    f32x4 kfa = tv ? *(const f32x4*)(Kf + rb)     : z4;
    f32x4 kfb = tv ? *(const f32x4*)(Kf + rb + 4) : z4;
    f32x4 qsa = tv ? *(const f32x4*)(Qs + rb)     : z4;
    f32x4 qsb = tv ? *(const f32x4*)(Qs + rb + 4) : z4;

    s16x8 fKfh, fKfl, fQsh, fQsl;
    split8(kfa, kfb, fKfh, fKfl);
    split8(qsa, qsb, fQsh, fQsl);

    float kjt  = tv ? kj[t]    : 0.f;
    float vft  = tv ? vf_fs[t] : 0.f;
    float invv = 1.f / (vft + 1e-5f);
    f32x4 qfa, qfb;
#pragma unroll
    for (int j = 0; j < 4; j++) {
        float qa = qsa[j], qb = qsb[j];
        qfa[j] = kjt * (qa - qa * qa * invv);
        qfb[j] = kjt * (qb - qb * qb * invv);
    }
    s16x8 fqfh, fqfl;
    split8(qfa, qfb, fqfh, fqfl);

    f32x4 zf = {0.f, 0.f, 0.f, 0.f};
    f32x4 aff = __builtin_amdgcn_mfma_f32_16x16x32_bf16(fKfh, fQf, zf, 0, 0, 0);
    aff = __builtin_amdgcn_mfma_f32_16x16x32_bf16(fKfl, fQf, aff, 0, 0, 0);
    f32x4 afs = __builtin_amdgcn_mfma_f32_16x16x32_bf16(fqfh, fKfh, zf, 0, 0, 0);
    afs = __builtin_amdgcn_mfma_f32_16x16x32_bf16(fqfl, fKfh, afs, 0, 0, 0);
    afs = __builtin_amdgcn_mfma_f32_16x16x32_bf16(fqfh, fKfl, afs, 0, 0, 0);
    afs = __builtin_amdgcn_mfma_f32_16x16x32_bf16(fqfl, fKfl, afs, 0, 0, 0);
    f32x4 asf = __builtin_amdgcn_mfma_f32_16x16x32_bf16(fQf, fKs, zf, 0, 0, 0);
    f32x4 ass = __builtin_amdgcn_mfma_f32_16x16x32_bf16(fKs, fQsh, zf, 0, 0, 0);
    ass = __builtin_amdgcn_mfma_f32_16x16x32_bf16(fKs, fQsl, ass, 0, 0, 0);

    __syncthreads();                                   // V staged
    s16x8 vbf0 = load_vfrag(sVf, wave * 32 + r16,      g);
    s16x8 vbf1 = load_vfrag(sVf, wave * 32 + 16 + r16, g);
    s16x8 vbs0 = load_vfrag(sVs, wave * 32 + r16,      g);
    s16x8 vbs1 = load_vfrag(sVs, wave * 32 + 16 + r16, g);

    s16x8 ph, pl;
    softmax_swapped(aff, g, ph, pl);
    ctx_to_lds(smem, ph, pl, vbf0, vbf1, 0, wave, g, r16);
    softmax_swapped(afs, g, ph, pl);
    ctx_to_lds(smem, ph, pl, vbf0, vbf1, 1, wave, g, r16);
    softmax_swapped(asf, g, ph, pl);
    ctx_to_lds(smem, ph, pl, vbs0, vbs1, 2, wave, g, r16);
    softmax_swapped(ass, g, ph, pl);
    ctx_to_lds(smem, ph, pl, vbs0, vbs1, 3, wave, g, r16);

    // ---- phase 2: out-projection. wave -> (mat, col-half); output 16x128 ----
    const int mat  = wave >> 1;
    const int half = wave & 1;

    f32x4 oacc[8];
#pragma unroll
    for (int ni = 0; ni < 8; ni++) oacc[ni] = (f32x4){0.f, 0.f, 0.f, 0.f};

#pragma unroll
    for (int ks = 0; ks < 8; ks++) {
        __syncthreads();                  // region0 free (V reads / prev w reads done)
        *(s16x8*)&smem[wo_row * 32 + (wslot0 << 3)] = wa;
        *(s16x8*)&smem[wo_row * 32 + (wslot1 << 3)] = wb;
        s16x8 na = wa, nb = wb;
        if (ks < 7) {                     // prefetch next tile under the MFMAs
            const ushort* wg2 = Wo + (size_t)wo_row * 256 + (ks + 1) * 32 + wo_cg0 * 8;
            na = *(const s16x8*)(wg2);
            nb = *(const s16x8*)(wg2 + 8);
        }
        __syncthreads();                  // w tile ready
        s16x8 a = zero8();
        if (r16 < 12)
            a = *(const s16x8*)&smem[8192 + mat * 3072 + r16 * 256 +
                                     (((ks * 4 + g) ^ (r16 & 7)) << 3)];
#pragma unroll
        for (int ni = 0; ni < 8; ni++) {
            int o = half * 128 + ni * 16 + r16;
            s16x8 b = *(const s16x8*)&smem[o * 32 + ((g ^ ((o >> 1) & 3)) << 3)];
            oacc[ni] = __builtin_amdgcn_mfma_f32_16x16x32_bf16(a, b, oacc[ni], 0, 0, 0);
        }
        wa = na; wb = nb;
    }

    // ---- store: D row = t = g*4+rg (t<12), col o; + bias ----
    float* outp = out + (size_t)mat * NEl + (size_t)bn * (Tn * Cn);
    if (g < 3) {
#pragma unroll
        for (int ni = 0; ni < 8; ni++) {
            int o = half * 128 + ni * 16 + r16;
            float bv = b_out[o];
#pragma unroll
            for (int rg = 0; rg < 4; rg++) {
                int tt = g * 4 + rg;
                outp[(size_t)tt * Cn + o] = oacc[ni][rg] + bv;
            }
        }
    }
}

// ---------------- host launcher ----------------
extern "C" void kernel_launch(void* const* d_in, const int* in_sizes, int n_in,
                              void* d_out, int out_size, void* d_ws, size_t ws_size,
                              hipStream_t stream) {
    (void)in_sizes; (void)n_in; (void)out_size; (void)ws_size;

    const float* flow_q  = (const float*)d_in[0];
    const float* flow_k  = (const float*)d_in[1];
    const float* flow_v  = (const float*)d_in[2];
    const float* speed_q = (const float*)d_in[3];
    const float* speed_k = (const float*)d_in[4];
    const float* speed_v = (const float*)d_in[5];
    const float* w_fq  = (const float*)d_in[6];
    const float* w_fk  = (const float*)d_in[7];
    const float* w_fv  = (const float*)d_in[8];
    const float* w_sq  = (const float*)d_in[9];
    const float* w_sk  = (const float*)d_in[10];
    const float* w_sv  = (const float*)d_in[11];
    const float* w_out = (const float*)d_in[12];
    const float* b_out = (const float*)d_in[13];
    const float* kj    = (const float*)d_in[14];
    const float* vf    = (const float*)d_in[15];

    char* ws = (char*)d_ws;
    size_t off = 0;
    auto alloc = [&](size_t bytes) -> void* {
        void* p = ws + off;
        off += (bytes + 255) & ~(size_t)255;
        return p;
    };
    ushort* Wh = (ushort*)alloc(7 * 65536 * 2);   // bf16 hi for 7 weight mats
    ushort* Wl = (ushort*)alloc(7 * 65536 * 2);   // bf16 lo residual
    ushort* Qf = (ushort*)alloc(NEl * 2);
    float*  Kf = (float*) alloc(NEl * 4);         // fp32: sensitive (z_fs logits)
    ushort* Vf = (ushort*)alloc(NEl * 2);
    float*  Qs = (float*) alloc(NEl * 4);         // fp32: feeds physics transform
    ushort* Ks = (ushort*)alloc(NEl * 2);
    ushort* Vs = (ushort*)alloc(NEl * 2);

    float* out = (float*)d_out;

    // 0) convert weights once per launch
    WPtrs wp;
    wp.src[0] = w_fq; wp.src[1] = w_fk; wp.src[2] = w_fv; wp.src[3] = w_sq;
    wp.src[4] = w_sk; wp.src[5] = w_sv; wp.src[6] = w_out;
    wconv_k<<<dim3(7 * 65536 / 256), 256, 0, stream>>>(wp, Wh, Wl);

    // 1a) 4 insensitive projections: 1-pass bf16, bf16 out
    GPtrs p1;
    p1.A[0] = flow_q;  p1.Wh[0] = Wh + 0 * 65536; p1.Wl[0] = Wl + 0 * 65536; p1.Y[0] = Qf;
    p1.A[1] = flow_v;  p1.Wh[1] = Wh + 2 * 65536; p1.Wl[1] = Wl + 2 * 65536; p1.Y[1] = Vf;
    p1.A[2] = speed_k; p1.Wh[2] = Wh + 4 * 65536; p1.Wl[2] = Wl + 4 * 65536; p1.Y[2] = Ks;
    p1.A[3] = speed_v; p1.Wh[3] = Wh + 5 * 65536; p1.Wl[3] = Wl + 5 * 65536; p1.Y[3] = Vs;
    gemm_proj_k<<<dim3(Mrows / 128, 4), 512, 0, stream>>>(p1);

    // 1b) 2 sensitive projections: split bf16x3 (~fp32), fp32 out
    GPtrs p2;
    p2.A[0] = flow_k;  p2.Wh[0] = Wh + 1 * 65536; p2.Wl[0] = Wl + 1 * 65536; p2.Y[0] = Kf;
    p2.A[1] = speed_q; p2.Wh[1] = Wh + 3 * 65536; p2.Wl[1] = Wl + 3 * 65536; p2.Y[1] = Qs;
    p2.A[2] = flow_k;  p2.Wh[2] = Wh + 1 * 65536; p2.Wl[2] = Wl + 1 * 65536; p2.Y[2] = Kf; // unused
    p2.A[3] = flow_k;  p2.Wh[3] = Wh + 1 * 65536; p2.Wl[3] = Wl + 1 * 65536; p2.Y[3] = Kf; // unused
    gemm_split_k<<<dim3(Mrows / 128, 2), 512, 0, stream>>>(p2);

    // 2) fused attention + out-projection (writes final output)
    attn_out_k<<<dim3(Bn * Nn), 512, 0, stream>>>(Qf, Kf, Vf, Qs, Ks, Vs, kj, vf,
                                                  Wh + 6 * 65536, b_out, out);
}